// Round 6
// baseline (110.029 us; speedup 1.0000x reference)
//
#include <hip/hip_runtime.h>
#include <math.h>

#define IMG  128
#define NCH  64
#define PADC 4
#define PADW 136               // 128 + 2*4
#define PLANE (PADW * PADW)    // 18496
#define NPIX (IMG * IMG)       // 16384

// Hsum planes (horizontal 3-tap of C, per part): [part][2][49][130][128],
// 1 zero row top/bottom, no col pad.
#define HPH 130
#define HPW 128
#define HPLANE (HPH * HPW)                  // 16640
#define NPART 4
#define HSTRIDE ((size_t)2 * 49 * HPLANE)   // floats per part

// border-zero bookkeeping
#define PHI_THREADS   262144                // 2*8*128*128 compute threads
#define PHI_BPP       2112                  // phi border floats per plane
#define PHI_BTOTAL    (128 * PHI_BPP)       // 270336
#define H_BPP         256                   // Hsum border floats per plane (2 rows)
#define H_BTOTAL      (392 * H_BPP)         // 100352 (98 planes * 4 parts)
#define TOTAL_THREADS (PHI_THREADS + PHI_BTOTAL + H_BTOTAL)  // 632832

// ---------------------------------------------------------------------------
// K1: phi[b][c][y][x] = sum_i w[c][i]*u[b][i][y][x] into padded planes
// phi_pad[2][64][136][136]; trailing blocks zero phi pad borders and the
// 2 zero rows of every Hsum plane.
// ---------------------------------------------------------------------------
__global__ __launch_bounds__(256) void k_phi(const float* __restrict__ u,
                                             const float* __restrict__ w,
                                             float* __restrict__ phi,
                                             float* __restrict__ Hs) {
  int t = blockIdx.x * 256 + threadIdx.x;

  if (t < PHI_THREADS) {
    int x  = t & 127;
    int y  = (t >> 7) & 127;
    int oc = (t >> 14) & 7;
    int b  = t >> 17;

    const float* up = u + (size_t)(b * NCH) * NPIX + y * IMG + x;
    const float* wr = w + oc * 8 * NCH;

    float acc[8];
#pragma unroll
    for (int k = 0; k < 8; ++k) acc[k] = 0.f;

#pragma unroll 16
    for (int i = 0; i < NCH; ++i) {
      float uv = up[(size_t)i * NPIX];
#pragma unroll
      for (int k = 0; k < 8; ++k) acc[k] += wr[k * NCH + i] * uv;
    }

    float* pp = phi + (size_t)(b * NCH + oc * 8) * PLANE + (y + PADC) * PADW + (x + PADC);
#pragma unroll
    for (int k = 0; k < 8; ++k) pp[(size_t)k * PLANE] = acc[k];
  } else if (t < PHI_THREADS + PHI_BTOTAL) {
    // phi border: rows 0..3,132..135 (all cols) + cols 0..3,132..135 (rows 4..131)
    int j = t - PHI_THREADS;
    int plane = j / PHI_BPP;
    int idx   = j - plane * PHI_BPP;
    int r, c;
    if (idx < 1088) { r = idx / 136; c = idx - (r * 136); r = (r < 4) ? r : r + 128; }
    else { int k = idx - 1088; r = (k >> 3) + 4; c = k & 7; c = (c < 4) ? c : c + 128; }
    phi[(size_t)plane * PLANE + r * PADW + c] = 0.f;
  } else if (t < TOTAL_THREADS) {
    // Hsum border: rows 0 and 129 of each [130][128] plane
    int j = t - (PHI_THREADS + PHI_BTOTAL);
    int plane = j >> 8;
    int idx   = j & 255;
    int r = (idx < 128) ? 0 : HPH - 1;
    int c = idx & 127;
    Hs[(size_t)plane * HPLANE + r * HPW + c] = 0.f;
  }
}

// ---------------------------------------------------------------------------
// K2: partial C_d + horizontal 3-tap fused. Per thread: 8 output px, acc over
// 10 px (x0-1..x0+8) so the h-tap is self-contained. Per channel: 8 float4
// loads -> 70 FMAs. h-tap applied once after the channel loop (linear).
// Hsum[part][b][d][row 1+y][x] = sum_{dx'=-1..1} C_d(y, x+dx')  (partial ch).
// ---------------------------------------------------------------------------
__global__ __launch_bounds__(256) void k_corr(const float* __restrict__ phi,
                                              float* __restrict__ Hs) {
  int t    = blockIdx.x * 256 + threadIdx.x;  // 4*2*7*128*16 = 114688 threads
  int xh   = t & 15;
  int y    = (t >> 4) & 127;
  int r    = t >> 11;           // 0..55 = part*14 + b*7 + dyI
  int part = r / 14;
  int rr   = r - part * 14;
  int b    = rr / 7;
  int dyI  = rr - b * 7;
  int x0   = xh * 8;
  int dy   = dyI - 3;

  const float* pb  = phi + (size_t)(b * NCH + part * 16) * PLANE;
  // padded col base x0 -> real x = x0-4 .. x0+11 (16 values, 4 aligned float4)
  const float* own = pb + (y + PADC) * PADW + x0;
  const float* nb  = pb + (y + dy + PADC) * PADW + x0;

  float acc[10][7];
#pragma unroll
  for (int p = 0; p < 10; ++p)
#pragma unroll
    for (int dxi = 0; dxi < 7; ++dxi) acc[p][dxi] = 0.f;

#pragma unroll 2
  for (int c = 0; c < 16; ++c) {
    float4 o0 = *(const float4*)(own + (size_t)c * PLANE);
    float4 o1 = *(const float4*)(own + (size_t)c * PLANE + 4);
    float4 o2 = *(const float4*)(own + (size_t)c * PLANE + 8);
    float4 o3 = *(const float4*)(own + (size_t)c * PLANE + 12);
    float4 n0 = *(const float4*)(nb + (size_t)c * PLANE);
    float4 n1 = *(const float4*)(nb + (size_t)c * PLANE + 4);
    float4 n2 = *(const float4*)(nb + (size_t)c * PLANE + 8);
    float4 n3 = *(const float4*)(nb + (size_t)c * PLANE + 12);
    float ov[16] = {o0.x, o0.y, o0.z, o0.w, o1.x, o1.y, o1.z, o1.w,
                    o2.x, o2.y, o2.z, o2.w, o3.x, o3.y, o3.z, o3.w};
    float nv[16] = {n0.x, n0.y, n0.z, n0.w, n1.x, n1.y, n1.z, n1.w,
                    n2.x, n2.y, n2.z, n2.w, n3.x, n3.y, n3.z, n3.w};
    // acc[p][dxi]: spatial x = x0-1+p ; phi(y,x) = ov[p+3]; phi(y+dy,x+dx) = nv[p+dxi]
#pragma unroll
    for (int p = 0; p < 10; ++p)
#pragma unroll
      for (int dxi = 0; dxi < 7; ++dxi)
        acc[p][dxi] += ov[p + 3] * nv[p + dxi];
  }

  float* Hp = Hs + part * HSTRIDE;
#pragma unroll
  for (int dxi = 0; dxi < 7; ++dxi) {
    int d = dyI * 7 + dxi;
    float h[8];
#pragma unroll
    for (int px = 0; px < 8; ++px)
      h[px] = acc[px][dxi] + acc[px + 1][dxi] + acc[px + 2][dxi];
    float* dst = Hp + ((size_t)(b * 49 + d) * HPH + (y + 1)) * HPW + x0;
    *(float4*)dst       = make_float4(h[0], h[1], h[2], h[3]);
    *(float4*)(dst + 4) = make_float4(h[4], h[5], h[6], h[7]);
  }
}

// ---------------------------------------------------------------------------
// K2.5: S_d = vertical 3-tap of (sum_part Hsum_part_d). 8 px/thread:
// 24 float4 loads -> 2 float4 stores.
// ---------------------------------------------------------------------------
__global__ __launch_bounds__(256) void k_box(const float* __restrict__ Hs,
                                             float* __restrict__ S) {
  int t  = blockIdx.x * 256 + threadIdx.x;   // 2*49*128*16 = 200704 threads
  int xh = t & 15;
  int y  = (t >> 4) & 127;
  int r  = t >> 11;             // b*49+d, 0..97
  int x0 = xh * 8;

  float acc[8] = {0.f, 0.f, 0.f, 0.f, 0.f, 0.f, 0.f, 0.f};
#pragma unroll
  for (int p = 0; p < NPART; ++p) {
    const float* base = Hs + p * HSTRIDE + ((size_t)r * HPH + y) * HPW + x0; // rows y..y+2 = real y-1..y+1
#pragma unroll
    for (int ry = 0; ry < 3; ++ry) {
      float4 a = *(const float4*)(base + ry * HPW);
      float4 b2 = *(const float4*)(base + ry * HPW + 4);
      acc[0] += a.x;  acc[1] += a.y;  acc[2] += a.z;  acc[3] += a.w;
      acc[4] += b2.x; acc[5] += b2.y; acc[6] += b2.z; acc[7] += b2.w;
    }
  }

  float* dst = S + (size_t)r * NPIX + y * IMG + x0;
  *(float4*)dst       = make_float4(acc[0], acc[1], acc[2], acc[3]);
  *(float4*)(dst + 4) = make_float4(acc[4], acc[5], acc[6], acc[7]);
}

// ---------------------------------------------------------------------------
// K3: s[d] = (p+d in-image) ? S_d(p) : 0 ; softmax over 49; coalesced store
// via LDS staging. 64-thread blocks -> 512 blocks cover all 256 CUs.
// ---------------------------------------------------------------------------
__global__ __launch_bounds__(64) void k_score(const float* __restrict__ S,
                                              float* __restrict__ out) {
  __shared__ float lds[64 * 49];
  int t = blockIdx.x * 64 + threadIdx.x;     // 2*128*128 = 32768 threads
  int x = t & 127;
  int y = (t >> 7) & 127;
  int b = t >> 14;

  const float* sp = S + (size_t)b * 49 * NPIX + y * IMG + x;

  float s[49];
#pragma unroll
  for (int dyI = 0; dyI < 7; ++dyI) {
    int qy = y + dyI - 3;
    bool yv = ((unsigned)qy < (unsigned)IMG);
#pragma unroll
    for (int dxi = 0; dxi < 7; ++dxi) {
      int d  = dyI * 7 + dxi;
      int qx = x + dxi - 3;
      float v = sp[(size_t)d * NPIX];          // coalesced over x
      s[d] = (yv && ((unsigned)qx < (unsigned)IMG)) ? v : 0.f;
    }
  }

  float m = s[0];
#pragma unroll
  for (int d = 1; d < 49; ++d) m = fmaxf(m, s[d]);
  float tot = 0.f;
#pragma unroll
  for (int d = 0; d < 49; ++d) {
    float e = __expf(s[d] - m);
    s[d] = e;
    tot += e;
  }
  float inv = 1.f / tot;

#pragma unroll
  for (int d = 0; d < 49; ++d) lds[threadIdx.x * 49 + d] = s[d] * inv;
  __syncthreads();

  // block's out chunk = 64*49 = 3136 contiguous floats = 784 float4
  float* ob = out + (size_t)blockIdx.x * (64 * 49);
  const float4* l4 = (const float4*)lds;
#pragma unroll
  for (int i = 0; i < 12; ++i)                 // 12*64 = 768 float4
    ((float4*)ob)[i * 64 + threadIdx.x] = l4[i * 64 + threadIdx.x];
  if (threadIdx.x < 16)                        // remaining 16 float4
    ((float4*)ob)[768 + threadIdx.x] = l4[768 + threadIdx.x];
}

// ---------------------------------------------------------------------------
extern "C" void kernel_launch(void* const* d_in, const int* in_sizes, int n_in,
                              void* d_out, int out_size, void* d_ws, size_t ws_size,
                              hipStream_t stream) {
  const float* u = (const float*)d_in[0];
  const float* w = (const float*)d_in[1];
  float* out = (float*)d_out;

  float* phi = (float*)d_ws;                           // 2*64*18496 = 2367488 floats
  float* Hs  = phi + (size_t)2 * NCH * PLANE;          // 4 * 1630720 floats (26.1 MB)
  float* S   = phi;                                    // alias: phi dead after k_corr
                                                       // (1605632 <= 2367488)

  k_phi  <<<(TOTAL_THREADS + 255) / 256, 256, 0, stream>>>(u, w, phi, Hs);
  k_corr <<<448, 256, 0, stream>>>(phi, Hs);
  k_box  <<<784, 256, 0, stream>>>(Hs, S);
  k_score<<<512, 64,  0, stream>>>(S, out);
}